// Round 13
// baseline (984.814 us; speedup 1.0000x reference)
//
#include <hip/hip_runtime.h>

// LSTM autoencoder, fused, TWO-LOOP pipelined kernel. 256 blocks (1/CU), 512 thr.
// r12 state: no spill (VGPR 124), 0 conflicts, VALUBusy 65%, 872us.
// r13 theory: d-loop is LDS-INSTRUCTION-PIPE bound (~100 b128/step ~ 1200cy).
//   (1) d1 -> Q=8 k-split, G=4, ALL 512 lanes: weights 16dw REGISTER-resident
//       (fits above d2's 96dw), operand = ONE b128/lane. d1 LDS 40->8 instrs.
//       wD1L (32KB) deleted. hsum8 reduce (e1-proven).
//   (2) x-staging spread 8 lanes/wave (kills e-loop wave-0 straggler).
// Tripwire: WRITE_SIZE > 65536KB => d1 regs re-spilled, revert.
//   e-loop (513): e1 all lanes (Q=8, 48dw) || e2 lag-1 wave 1 || x-stage 8/wave.
//   d-loop (513): d2 all lanes (Q=4, 96dw) || d1 all lanes (Q=8, 16dw) lag-1 lead.
// 2-parity rings; DPP-only reduces; quad-split activation; 1 barrier/step.

#define BB 256
#define TT 512

typedef _Float16 half2v __attribute__((ext_vector_type(2)));

static __device__ __forceinline__ float dot2(half2v a, half2v b, float c){
  return __builtin_amdgcn_fdot2(a,b,c,false);
}
template<int CTRL>
static __device__ __forceinline__ float qb(float v){
  return __int_as_float(__builtin_amdgcn_update_dpp(0, __float_as_int(v), CTRL, 0xF, 0xF, true));
}
static __device__ __forceinline__ float qsum1(float v){ return v + qb<0xB1>(v); }
static __device__ __forceinline__ float qsum2(float v){ return v + qb<0x4E>(v); }
static __device__ __forceinline__ float hsum8(float v){       // 8-lane-group sum
  v = qsum1(v); v = qsum2(v); return v + qb<0x141>(v);        // row_half_mirror
}
static __device__ __forceinline__ unsigned packh2(float lo, float hi){
  half2v p; p.x=(_Float16)lo; p.y=(_Float16)hi;
  return __builtin_bit_cast(unsigned, p);
}
static __device__ __forceinline__ half2v ash2(unsigned u){ return __builtin_bit_cast(half2v,u); }
static __device__ __forceinline__ half2v mkh2(float lo, float hi){
  half2v p; p.x=(_Float16)lo; p.y=(_Float16)hi; return p;
}

// Quad lanes hold identical a0..a3=(i,f,g,o). Lane q activates gate q (tanh
// via 2*sigm(2v)-1), DPP quad-broadcast, update c, return h. (r7-r12 proven.)
static __device__ __forceinline__ float lstm_update(int q, float a0, float a1,
                                                    float a2, float a3, float& c){
  float mine = a0;
  mine = (q==1) ? a1 : mine;
  mine = (q==2) ? a2 : mine;
  mine = (q==3) ? a3 : mine;
  const bool isg = (q==2);
  const float arg = isg ? (mine+mine) : mine;
  const float s   = 1.0f/(1.0f + __expf(-arg));
  const float act = isg ? (s+s-1.0f) : s;
  const float bi = qb<0x00>(act);
  const float bf = qb<0x55>(act);
  const float bg = qb<0xAA>(act);
  const float bo = qb<0xFF>(act);
  c = bf*c + bi*bg;
  const float s2 = 1.0f/(1.0f + __expf(-(c+c)));
  return bo*(s2+s2-1.0f);
}

__global__ void __launch_bounds__(512, 2) k_fused(
    const float* __restrict__ x,
    const float* __restrict__ WihE1, const float* __restrict__ WhhE1,
    const float* __restrict__ bihE1, const float* __restrict__ bhhE1,
    const float* __restrict__ WihE2, const float* __restrict__ WhhE2,
    const float* __restrict__ bihE2, const float* __restrict__ bhhE2,
    const float* __restrict__ WihD1, const float* __restrict__ WhhD1,
    const float* __restrict__ bihD1, const float* __restrict__ bhhD1,
    const float* __restrict__ WihD2, const float* __restrict__ WhhD2,
    const float* __restrict__ bihD2, const float* __restrict__ bhhD2,
    float* __restrict__ out)
{
  const int b = blockIdx.x, tid = threadIdx.x;

  __shared__ unsigned vhE [2*96];   // e1 operand ring: x 64dw || h1 32dw (f16)
  __shared__ unsigned e2op[2*48];   // e2 ring: relu(h1) 32dw || h2 8dw || pad0 8dw
  __shared__ unsigned dop [2*96];   // d2 ring: relu(hd1) 32dw || hd2 64dw
  __shared__ unsigned vhD1[2*32];   // d1 h ring
  __shared__ float4   bD2L[128];    // d2 bias per unit (4 gates)
  __shared__ float4   pD1L[64];     // d1 latent-proj+bias per unit (4 gates)
  __shared__ float    latF[16];

  //================= E-LOOP: e1 || e2(lag-1) || x-stage =================
  {
    const int o = tid & 7, j = tid >> 3;          // e1: all lanes, unit j, slice o
    half2v w1[4][12];
    float bias1[4];
#pragma unroll
    for (int g=0; g<4; ++g){
      const int row = g*64 + j;
      bias1[g] = (o==0) ? (bihE1[row]+bhhE1[row]) : 0.0f;
#pragma unroll
      for (int m=0;m<12;++m){
        const int k0 = 24*o + 2*m;                // concat {x:128, h:64}
        const float lo = (k0   < 128)? WihE1[row*128+k0]   : WhhE1[row*64 + (k0-128)];
        const float hi = (k0+1 < 128)? WihE1[row*128+k0+1] : WhhE1[row*64 + (k0+1-128)];
        w1[g][m] = mkh2(lo,hi);
      }
    }
    // e2: wave 1 (tid 64..127). unit j2 in [0,16), slice q2. K=96 {h1:64,h2:16,pad:16}
    const bool e2act = (tid >= 64 && tid < 128);
    const int q2 = tid & 3, j2 = (tid - 64) >> 2;
    half2v w2[4][12];
    float bias2[4] = {0.f,0.f,0.f,0.f};
    if (e2act){
#pragma unroll
      for (int g=0; g<4; ++g){
        const int row = g*16 + j2;
        bias2[g] = (q2==0) ? (bihE2[row]+bhhE2[row]) : 0.0f;
#pragma unroll
        for (int m=0;m<12;++m){
          const int k0 = 24*q2 + 2*m;
          float lo = 0.0f, hi = 0.0f;
          if (k0 < 64)        lo = WihE2[row*64+k0];
          else if (k0 < 80)   lo = WhhE2[row*16 + (k0-64)];
          if (k0+1 < 64)      hi = WihE2[row*64+k0+1];
          else if (k0+1 < 80) hi = WhhE2[row*16 + (k0+1-64)];
          w2[g][m] = mkh2(lo,hi);
        }
      }
    }
    // x staging: 8 lanes per wave ((tid&63)<8), depth-2 register prefetch.
    // xl in [0,64): lane covers x float pair (2xl, 2xl+1).
    const bool xact = ((tid & 63) < 8);
    const int  xl   = ((tid >> 6) << 3) | (tid & 7);
    const float* xrow = x + (size_t)b * (TT*128);
    float2 xa, xb;
    if (xact){
      float2 v0 = *(const float2*)(xrow + 2*xl);
      vhE[xl] = packh2(v0.x, v0.y);               // x(0) -> parity 0
      xa = *(const float2*)(xrow + 128 + 2*xl);
      xb = *(const float2*)(xrow + 256 + 2*xl);
    }
    if (tid >= 128 && tid < 160) vhE[64 + (tid-128)] = 0u;  // h1(-1)=0 (parity 0)
    if (tid >= 160 && tid < 256) e2op[tid-160] = 0u;        // h2(-1)+pads=0 (both par.)
    float c1 = 0.0f, c2 = 0.0f;
    __syncthreads();

#define XSTAGE(T, NXT) do{ if (xact){                                          \
      vhE[(NXT)*96 + xl] = packh2(xa.x, xa.y);                                 \
      xa = xb;                                                                 \
      const int t3_ = ((T)+3 < TT) ? ((T)+3) : (TT-1);                         \
      xb = *(const float2*)(xrow + (size_t)t3_*128 + 2*xl);                    \
    } }while(0)

#define E1STEP(T, CUR) do{                                                     \
      float a0=bias1[0], a1=bias1[1], a2=bias1[2], a3=bias1[3];                \
      const uint4* vp = (const uint4*)(vhE + (CUR)*96 + o*12);                 \
      _Pragma("unroll")                                                        \
      for (int r=0;r<3;++r){                                                   \
        const uint4 u = vp[r];                                                 \
        const half2v o0=ash2(u.x), o1=ash2(u.y), o2=ash2(u.z), o3=ash2(u.w);   \
        a0=dot2(w1[0][4*r+0],o0,a0); a1=dot2(w1[1][4*r+0],o0,a1);              \
        a2=dot2(w1[2][4*r+0],o0,a2); a3=dot2(w1[3][4*r+0],o0,a3);              \
        a0=dot2(w1[0][4*r+1],o1,a0); a1=dot2(w1[1][4*r+1],o1,a1);              \
        a2=dot2(w1[2][4*r+1],o1,a2); a3=dot2(w1[3][4*r+1],o1,a3);              \
        a0=dot2(w1[0][4*r+2],o2,a0); a1=dot2(w1[1][4*r+2],o2,a1);              \
        a2=dot2(w1[2][4*r+2],o2,a2); a3=dot2(w1[3][4*r+2],o2,a3);              \
        a0=dot2(w1[0][4*r+3],o3,a0); a1=dot2(w1[1][4*r+3],o3,a1);              \
        a2=dot2(w1[2][4*r+3],o3,a2); a3=dot2(w1[3][4*r+3],o3,a3);              \
      }                                                                        \
      a0=hsum8(a0); a1=hsum8(a1); a2=hsum8(a2); a3=hsum8(a3);                  \
      const float h = lstm_update(o & 3, a0, a1, a2, a3, c1);                  \
      if (o == 0){                                                             \
        ((_Float16*)(vhE + ((CUR)^1)*96))[128 + j] = (_Float16)h;              \
        ((_Float16*)(e2op + (CUR)*48))[j]          = (_Float16)fmaxf(h, 0.0f); \
      }                                                                        \
    }while(0)

#define E2STEP(T2, CP) do{ if (e2act){                                         \
      float a0=bias2[0], a1=bias2[1], a2=bias2[2], a3=bias2[3];                \
      const uint4* vp = (const uint4*)(e2op + (CP)*48 + q2*12);                \
      _Pragma("unroll")                                                        \
      for (int r=0;r<3;++r){                                                   \
        const uint4 u = vp[r];                                                 \
        const half2v o0=ash2(u.x), o1=ash2(u.y), o2=ash2(u.z), o3=ash2(u.w);   \
        a0=dot2(w2[0][4*r+0],o0,a0); a1=dot2(w2[1][4*r+0],o0,a1);              \
        a2=dot2(w2[2][4*r+0],o0,a2); a3=dot2(w2[3][4*r+0],o0,a3);              \
        a0=dot2(w2[0][4*r+1],o1,a0); a1=dot2(w2[1][4*r+1],o1,a1);              \
        a2=dot2(w2[2][4*r+1],o1,a2); a3=dot2(w2[3][4*r+1],o1,a3);              \
        a0=dot2(w2[0][4*r+2],o2,a0); a1=dot2(w2[1][4*r+2],o2,a1);              \
        a2=dot2(w2[2][4*r+2],o2,a2); a3=dot2(w2[3][4*r+2],o2,a3);              \
        a0=dot2(w2[0][4*r+3],o3,a0); a1=dot2(w2[1][4*r+3],o3,a1);              \
        a2=dot2(w2[2][4*r+3],o3,a2); a3=dot2(w2[3][4*r+3],o3,a3);              \
      }                                                                        \
      a0=qsum2(qsum1(a0)); a1=qsum2(qsum1(a1));                                \
      a2=qsum2(qsum1(a2)); a3=qsum2(qsum1(a3));                                \
      const float h = lstm_update(q2, a0, a1, a2, a3, c2);                     \
      if (q2 == 0){                                                            \
        ((_Float16*)(e2op + ((CP)^1)*48))[64 + j2] = (_Float16)h;              \
        if ((T2) == TT-1) latF[j2] = fmaxf(h, 0.0f);                           \
      }                                                                        \
    } }while(0)

    // peel t=0 (cur=0)
    XSTAGE(0, 1); E1STEP(0, 0);
    __syncthreads();
    // pairs t=1(odd,cur1), t+1(even,cur0) for t=1..509
    for (int t = 1; t <= TT-3; t += 2){
      XSTAGE(t, 0);   E1STEP(t, 1);   E2STEP(t-1, 0);
      __syncthreads();
      XSTAGE(t+1, 1); E1STEP(t+1, 0); E2STEP(t, 1);
      __syncthreads();
    }
    // t=511 (cur=1)
    XSTAGE(TT-1, 0); E1STEP(TT-1, 1); E2STEP(TT-2, 0);
    __syncthreads();
    // t=512: e2 tail only (t2=511, parity 1)
    E2STEP(TT-1, 1);
    __syncthreads();
#undef XSTAGE
#undef E1STEP
#undef E2STEP
  }
  __syncthreads();
  asm volatile("" ::: "memory");   // e-loop weights die here

  //================= D-LOOP: d2 (first) || d1(lag-1 lead, reg weights) =================
  {
    // Fill bD2L[128]: per-unit d2 bias (4 gates)
    if (tid < 128){
      float4 bb;
      bb.x = bihD2[0*128+tid] + bhhD2[0*128+tid];
      bb.y = bihD2[1*128+tid] + bhhD2[1*128+tid];
      bb.z = bihD2[2*128+tid] + bhhD2[2*128+tid];
      bb.w = bihD2[3*128+tid] + bhhD2[3*128+tid];
      bD2L[tid] = bb;
    }
    // Fill pD1L[64]: per-unit d1 latent-projection + bias (latF ready)
    if (tid < 64){
      float4 pp;
#pragma unroll
      for (int g=0; g<4; ++g){
        const int row = g*64 + tid;
        float a = bihD1[row] + bhhD1[row];
#pragma unroll
        for (int i=0;i<16;++i) a = fmaf(WihD1[row*16+i], latF[i], a);
        (&pp.x)[g] = a;
      }
      pD1L[tid] = pp;
    }

    const int qd = tid & 3, jd = tid >> 2;        // d2: unit jd in [0,128), slice qd
    half2v wD2[4][24];
#pragma unroll
    for (int g=0; g<4; ++g){
      const int row = g*128 + jd;
#pragma unroll
      for (int m=0;m<24;++m){
        const int k0 = 48*qd + 2*m;               // concat {x:64, h:128}
        const float lo = (k0   < 64)? WihD2[row*64+k0]   : WhhD2[row*128+(k0-64)];
        const float hi = (k0+1 < 64)? WihD2[row*64+k0+1] : WhhD2[row*128+(k0+1-64)];
        wD2[g][m] = mkh2(lo,hi);
      }
    }
    // d1: ALL lanes. unit j1d = tid>>3 in [0,64), slice o8 = tid&7 (K=64 -> 8 f16).
    // Weights 4 gates x 4 f16x2 = 16dw, register-resident.
    const int o8 = tid & 7, j1d = tid >> 3;
    half2v wd1[4][4];
#pragma unroll
    for (int g=0; g<4; ++g){
      const int row = g*64 + j1d;
#pragma unroll
      for (int m=0;m<4;++m){
        const int k0 = o8*8 + 2*m;
        wd1[g][m] = mkh2(WhhD1[row*64+k0], WhhD1[row*64+k0+1]);
      }
    }
    if (tid < 64)                dop[32 + tid] = 0u;   // hd2(-1)=0 (parity 0)
    if (tid >= 64 && tid < 96)   vhD1[tid-64] = 0u;    // hd1(-1)=0 (parity 0)
    float cd1 = 0.0f, cd2 = 0.0f;
    float* orow = out + (size_t)b * (TT*128);
    __syncthreads();

#define D2STEP(T2, C2P) do{                                                    \
      float a0=0.f, a1=0.f, a2=0.f, a3=0.f;                                    \
      const uint4* vp = (const uint4*)(dop + (C2P)*96 + qd*24);                \
      _Pragma("unroll")                                                        \
      for (int r=0;r<6;++r){                                                   \
        const uint4 u = vp[r];                                                 \
        const half2v o0=ash2(u.x),o1=ash2(u.y),o2=ash2(u.z),o3=ash2(u.w);      \
        a0=dot2(wD2[0][4*r+0],o0,a0); a1=dot2(wD2[1][4*r+0],o0,a1);            \
        a2=dot2(wD2[2][4*r+0],o0,a2); a3=dot2(wD2[3][4*r+0],o0,a3);            \
        a0=dot2(wD2[0][4*r+1],o1,a0); a1=dot2(wD2[1][4*r+1],o1,a1);            \
        a2=dot2(wD2[2][4*r+1],o1,a2); a3=dot2(wD2[3][4*r+1],o1,a3);            \
        a0=dot2(wD2[0][4*r+2],o2,a0); a1=dot2(wD2[1][4*r+2],o2,a1);            \
        a2=dot2(wD2[2][4*r+2],o2,a2); a3=dot2(wD2[3][4*r+2],o2,a3);            \
        a0=dot2(wD2[0][4*r+3],o3,a0); a1=dot2(wD2[1][4*r+3],o3,a1);            \
        a2=dot2(wD2[2][4*r+3],o3,a2); a3=dot2(wD2[3][4*r+3],o3,a3);            \
      }                                                                        \
      a0=qsum2(qsum1(a0)); a1=qsum2(qsum1(a1));                                \
      a2=qsum2(qsum1(a2)); a3=qsum2(qsum1(a3));                                \
      const float4 bb = bD2L[jd];                                              \
      a0 += bb.x; a1 += bb.y; a2 += bb.z; a3 += bb.w;                          \
      const float h = lstm_update(qd, a0, a1, a2, a3, cd2);                    \
      if (qd==0){                                                              \
        ((_Float16*)(dop + ((C2P)^1)*96))[64 + jd] = (_Float16)h;              \
        orow[(size_t)(T2)*128 + jd] = h;                                       \
      }                                                                        \
    }while(0)

#define D1STEP(T, CUR) do{                                                     \
      const uint4 u = *(const uint4*)(vhD1 + (CUR)*32 + o8*4);                 \
      const half2v o0=ash2(u.x),o1=ash2(u.y),o2=ash2(u.z),o3=ash2(u.w);        \
      float a0=0.f, a1=0.f, a2=0.f, a3=0.f;                                    \
      a0=dot2(wd1[0][0],o0,a0); a1=dot2(wd1[1][0],o0,a1);                      \
      a2=dot2(wd1[2][0],o0,a2); a3=dot2(wd1[3][0],o0,a3);                      \
      a0=dot2(wd1[0][1],o1,a0); a1=dot2(wd1[1][1],o1,a1);                      \
      a2=dot2(wd1[2][1],o1,a2); a3=dot2(wd1[3][1],o1,a3);                      \
      a0=dot2(wd1[0][2],o2,a0); a1=dot2(wd1[1][2],o2,a1);                      \
      a2=dot2(wd1[2][2],o2,a2); a3=dot2(wd1[3][2],o2,a3);                      \
      a0=dot2(wd1[0][3],o3,a0); a1=dot2(wd1[1][3],o3,a1);                      \
      a2=dot2(wd1[2][3],o3,a2); a3=dot2(wd1[3][3],o3,a3);                      \
      a0=hsum8(a0); a1=hsum8(a1); a2=hsum8(a2); a3=hsum8(a3);                  \
      const float4 pj = pD1L[j1d];                                             \
      a0 += pj.x; a1 += pj.y; a2 += pj.z; a3 += pj.w;                          \
      const float h = lstm_update(tid & 3, a0, a1, a2, a3, cd1);               \
      if (o8==0){                                                              \
        ((_Float16*)(vhD1 + ((CUR)^1)*32))[j1d] = (_Float16)h;                 \
        ((_Float16*)(dop + (CUR)*96))[j1d]      = (_Float16)fmaxf(h,0.0f);     \
      }                                                                        \
    }while(0)

    // peel t=0 (cur=0): d1 only
    D1STEP(0, 0);
    __syncthreads();
    // pairs t=odd(cur1), t+1=even(cur0) for t=1..509
    for (int t = 1; t <= TT-3; t += 2){
      D2STEP(t-1, 0); D1STEP(t, 1);
      __syncthreads();
      D2STEP(t, 1);   D1STEP(t+1, 0);
      __syncthreads();
    }
    // t=511 (cur=1)
    D2STEP(TT-2, 0); D1STEP(TT-1, 1);
    __syncthreads();
    // t=512: d2 tail only (t2=511, parity 1)
    D2STEP(TT-1, 1);
#undef D2STEP
#undef D1STEP
  }
}

extern "C" void kernel_launch(void* const* d_in, const int* in_sizes, int n_in,
                              void* d_out, int out_size, void* d_ws, size_t ws_size,
                              hipStream_t stream) {
  const float* x      = (const float*)d_in[0];
  const float* WihE1  = (const float*)d_in[1];
  const float* WhhE1  = (const float*)d_in[2];
  const float* bihE1  = (const float*)d_in[3];
  const float* bhhE1  = (const float*)d_in[4];
  const float* WihE2  = (const float*)d_in[5];
  const float* WhhE2  = (const float*)d_in[6];
  const float* bihE2  = (const float*)d_in[7];
  const float* bhhE2  = (const float*)d_in[8];
  const float* WihD1  = (const float*)d_in[9];
  const float* WhhD1  = (const float*)d_in[10];
  const float* bihD1  = (const float*)d_in[11];
  const float* bhhD1  = (const float*)d_in[12];
  const float* WihD2  = (const float*)d_in[13];
  const float* WhhD2  = (const float*)d_in[14];
  const float* bihD2  = (const float*)d_in[15];
  const float* bhhD2  = (const float*)d_in[16];
  float* out = (float*)d_out;

  k_fused<<<BB, 512, 0, stream>>>(x,
      WihE1, WhhE1, bihE1, bhhE1,
      WihE2, WhhE2, bihE2, bhhE2,
      WihD1, WhhD1, bihD1, bhhD1,
      WihD2, WhhD2, bihD2, bhhD2,
      out);
}

// Round 14
// 775.361 us; speedup vs baseline: 1.2701x; 1.2701x over previous
//
#include <hip/hip_runtime.h>

// LSTM autoencoder, fused, TWO-LOOP pipelined kernel. 256 blocks (1/CU), 512 thr.
// = r12 (best, 872us; no spill, 0 conflicts) + fast-rcp activations.
// Issue law (r13 lesson): a code block costs FULL wave-issue on every wave with
// >=1 active lane — concentrate small roles (e2 on wave 1, x-stage on wave 0,
// d1 on waves 0-3); k-split only pays if per-lane dot chain shrinks faster
// than duplicated overhead. This round cuts the IEEE-division sequences in
// sigm/tanh (v_div_scale/fmas/fixup ~6-8 instrs) to v_rcp_f32 (1 instr).
//   e-loop (513): e1 all lanes (Q=8, 48dw) || e2 lag-1 wave 1 || x-stage wave 0.
//   d-loop (513): d2 all lanes (Q=4, 96dw) || d1 lag-1 lead lanes<256 (weights in
//                 LDS 32KB [r][lane][4dw]); bias/proj via LDS quad-broadcast.
// 2-parity rings; DPP-only reduces; quad-split activation; 1 barrier/step;
// unrolled x2 with compile-time parities.

#define BB 256
#define TT 512

typedef _Float16 half2v __attribute__((ext_vector_type(2)));

static __device__ __forceinline__ float dot2(half2v a, half2v b, float c){
  return __builtin_amdgcn_fdot2(a,b,c,false);
}
template<int CTRL>
static __device__ __forceinline__ float qb(float v){
  return __int_as_float(__builtin_amdgcn_update_dpp(0, __float_as_int(v), CTRL, 0xF, 0xF, true));
}
static __device__ __forceinline__ float qsum1(float v){ return v + qb<0xB1>(v); }
static __device__ __forceinline__ float qsum2(float v){ return v + qb<0x4E>(v); }
static __device__ __forceinline__ float hsum8(float v){       // 8-lane-group sum
  v = qsum1(v); v = qsum2(v); return v + qb<0x141>(v);        // row_half_mirror
}
static __device__ __forceinline__ float rcp_(float v){ return __builtin_amdgcn_rcpf(v); }
static __device__ __forceinline__ unsigned packh2(float lo, float hi){
  half2v p; p.x=(_Float16)lo; p.y=(_Float16)hi;
  return __builtin_bit_cast(unsigned, p);
}
static __device__ __forceinline__ half2v ash2(unsigned u){ return __builtin_bit_cast(half2v,u); }
static __device__ __forceinline__ half2v mkh2(float lo, float hi){
  half2v p; p.x=(_Float16)lo; p.y=(_Float16)hi; return p;
}

// Quad lanes hold identical a0..a3=(i,f,g,o). Lane q activates gate q (tanh
// via 2*sigm(2v)-1), DPP quad-broadcast, update c, return h. (r7-r12 proven.)
// r14: divisions replaced by v_rcp_f32 (~1 ulp; absmax margin is 4x).
static __device__ __forceinline__ float lstm_update(int q, float a0, float a1,
                                                    float a2, float a3, float& c){
  float mine = a0;
  mine = (q==1) ? a1 : mine;
  mine = (q==2) ? a2 : mine;
  mine = (q==3) ? a3 : mine;
  const bool isg = (q==2);
  const float arg = isg ? (mine+mine) : mine;
  const float s   = rcp_(1.0f + __expf(-arg));
  const float act = isg ? (s+s-1.0f) : s;
  const float bi = qb<0x00>(act);
  const float bf = qb<0x55>(act);
  const float bg = qb<0xAA>(act);
  const float bo = qb<0xFF>(act);
  c = bf*c + bi*bg;
  const float s2 = rcp_(1.0f + __expf(-(c+c)));
  return bo*(s2+s2-1.0f);
}

__global__ void __launch_bounds__(512, 2) k_fused(
    const float* __restrict__ x,
    const float* __restrict__ WihE1, const float* __restrict__ WhhE1,
    const float* __restrict__ bihE1, const float* __restrict__ bhhE1,
    const float* __restrict__ WihE2, const float* __restrict__ WhhE2,
    const float* __restrict__ bihE2, const float* __restrict__ bhhE2,
    const float* __restrict__ WihD1, const float* __restrict__ WhhD1,
    const float* __restrict__ bihD1, const float* __restrict__ bhhD1,
    const float* __restrict__ WihD2, const float* __restrict__ WhhD2,
    const float* __restrict__ bihD2, const float* __restrict__ bhhD2,
    float* __restrict__ out)
{
  const int b = blockIdx.x, tid = threadIdx.x;

  __shared__ unsigned wD1L[8*1024]; // 32KB d1 weights: [r 0..7][lane 0..255][4dw]
  __shared__ unsigned vhE [2*96];   // e1 operand ring: x 64dw || h1 32dw (f16)
  __shared__ unsigned e2op[2*48];   // e2 ring: relu(h1) 32dw || h2 8dw || pad0 8dw
  __shared__ unsigned dop [2*96];   // d2 ring: relu(hd1) 32dw || hd2 64dw
  __shared__ unsigned vhD1[2*32];   // d1 h ring
  __shared__ float4   bD2L[128];    // d2 bias per unit (4 gates)
  __shared__ float4   pD1L[64];     // d1 latent-proj+bias per unit (4 gates)
  __shared__ float    latF[16];

  //================= E-LOOP: e1 || e2(lag-1) || x-stage =================
  {
    const int o = tid & 7, j = tid >> 3;          // e1: all lanes, unit j, slice o
    half2v w1[4][12];
    float bias1[4];
#pragma unroll
    for (int g=0; g<4; ++g){
      const int row = g*64 + j;
      bias1[g] = (o==0) ? (bihE1[row]+bhhE1[row]) : 0.0f;
#pragma unroll
      for (int m=0;m<12;++m){
        const int k0 = 24*o + 2*m;                // concat {x:128, h:64}
        const float lo = (k0   < 128)? WihE1[row*128+k0]   : WhhE1[row*64 + (k0-128)];
        const float hi = (k0+1 < 128)? WihE1[row*128+k0+1] : WhhE1[row*64 + (k0+1-128)];
        w1[g][m] = mkh2(lo,hi);
      }
    }
    // e2: wave 1 (tid 64..127). unit j2 in [0,16), slice q2. K=96 {h1:64,h2:16,pad:16}
    const bool e2act = (tid >= 64 && tid < 128);
    const int q2 = tid & 3, j2 = (tid - 64) >> 2;
    half2v w2[4][12];
    float bias2[4] = {0.f,0.f,0.f,0.f};
    if (e2act){
#pragma unroll
      for (int g=0; g<4; ++g){
        const int row = g*16 + j2;
        bias2[g] = (q2==0) ? (bihE2[row]+bhhE2[row]) : 0.0f;
#pragma unroll
        for (int m=0;m<12;++m){
          const int k0 = 24*q2 + 2*m;
          float lo = 0.0f, hi = 0.0f;
          if (k0 < 64)        lo = WihE2[row*64+k0];
          else if (k0 < 80)   lo = WhhE2[row*16 + (k0-64)];
          if (k0+1 < 64)      hi = WihE2[row*64+k0+1];
          else if (k0+1 < 80) hi = WhhE2[row*16 + (k0+1-64)];
          w2[g][m] = mkh2(lo,hi);
        }
      }
    }
    // x staging: lanes 0..63 (also run e1), depth-2 register prefetch
    const bool xact = (tid < 64);
    const float* xrow = x + (size_t)b * (TT*128);
    float2 xa, xb;
    if (xact){
      float2 v0 = *(const float2*)(xrow + 2*tid);
      vhE[tid] = packh2(v0.x, v0.y);              // x(0) -> parity 0
      xa = *(const float2*)(xrow + 128 + 2*tid);
      xb = *(const float2*)(xrow + 256 + 2*tid);
    }
    if (tid >= 128 && tid < 160) vhE[64 + (tid-128)] = 0u;  // h1(-1)=0 (parity 0)
    if (tid >= 160 && tid < 256) e2op[tid-160] = 0u;        // h2(-1)+pads=0 (both par.)
    float c1 = 0.0f, c2 = 0.0f;
    __syncthreads();

#define XSTAGE(T, NXT) do{ if (xact){                                          \
      vhE[(NXT)*96 + tid] = packh2(xa.x, xa.y);                                \
      xa = xb;                                                                 \
      const int t3_ = ((T)+3 < TT) ? ((T)+3) : (TT-1);                         \
      xb = *(const float2*)(xrow + (size_t)t3_*128 + 2*tid);                   \
    } }while(0)

#define E1STEP(T, CUR) do{                                                     \
      float a0=bias1[0], a1=bias1[1], a2=bias1[2], a3=bias1[3];                \
      const uint4* vp = (const uint4*)(vhE + (CUR)*96 + o*12);                 \
      _Pragma("unroll")                                                        \
      for (int r=0;r<3;++r){                                                   \
        const uint4 u = vp[r];                                                 \
        const half2v o0=ash2(u.x), o1=ash2(u.y), o2=ash2(u.z), o3=ash2(u.w);   \
        a0=dot2(w1[0][4*r+0],o0,a0); a1=dot2(w1[1][4*r+0],o0,a1);              \
        a2=dot2(w1[2][4*r+0],o0,a2); a3=dot2(w1[3][4*r+0],o0,a3);              \
        a0=dot2(w1[0][4*r+1],o1,a0); a1=dot2(w1[1][4*r+1],o1,a1);              \
        a2=dot2(w1[2][4*r+1],o1,a2); a3=dot2(w1[3][4*r+1],o1,a3);              \
        a0=dot2(w1[0][4*r+2],o2,a0); a1=dot2(w1[1][4*r+2],o2,a1);              \
        a2=dot2(w1[2][4*r+2],o2,a2); a3=dot2(w1[3][4*r+2],o2,a3);              \
        a0=dot2(w1[0][4*r+3],o3,a0); a1=dot2(w1[1][4*r+3],o3,a1);              \
        a2=dot2(w1[2][4*r+3],o3,a2); a3=dot2(w1[3][4*r+3],o3,a3);              \
      }                                                                        \
      a0=hsum8(a0); a1=hsum8(a1); a2=hsum8(a2); a3=hsum8(a3);                  \
      const float h = lstm_update(o & 3, a0, a1, a2, a3, c1);                  \
      if (o == 0){                                                             \
        ((_Float16*)(vhE + ((CUR)^1)*96))[128 + j] = (_Float16)h;              \
        ((_Float16*)(e2op + (CUR)*48))[j]          = (_Float16)fmaxf(h, 0.0f); \
      }                                                                        \
    }while(0)

#define E2STEP(T2, CP) do{ if (e2act){                                         \
      float a0=bias2[0], a1=bias2[1], a2=bias2[2], a3=bias2[3];                \
      const uint4* vp = (const uint4*)(e2op + (CP)*48 + q2*12);                \
      _Pragma("unroll")                                                        \
      for (int r=0;r<3;++r){                                                   \
        const uint4 u = vp[r];                                                 \
        const half2v o0=ash2(u.x), o1=ash2(u.y), o2=ash2(u.z), o3=ash2(u.w);   \
        a0=dot2(w2[0][4*r+0],o0,a0); a1=dot2(w2[1][4*r+0],o0,a1);              \
        a2=dot2(w2[2][4*r+0],o0,a2); a3=dot2(w2[3][4*r+0],o0,a3);              \
        a0=dot2(w2[0][4*r+1],o1,a0); a1=dot2(w2[1][4*r+1],o1,a1);              \
        a2=dot2(w2[2][4*r+1],o1,a2); a3=dot2(w2[3][4*r+1],o1,a3);              \
        a0=dot2(w2[0][4*r+2],o2,a0); a1=dot2(w2[1][4*r+2],o2,a1);              \
        a2=dot2(w2[2][4*r+2],o2,a2); a3=dot2(w2[3][4*r+2],o2,a3);              \
        a0=dot2(w2[0][4*r+3],o3,a0); a1=dot2(w2[1][4*r+3],o3,a1);              \
        a2=dot2(w2[2][4*r+3],o3,a2); a3=dot2(w2[3][4*r+3],o3,a3);              \
      }                                                                        \
      a0=qsum2(qsum1(a0)); a1=qsum2(qsum1(a1));                                \
      a2=qsum2(qsum1(a2)); a3=qsum2(qsum1(a3));                                \
      const float h = lstm_update(q2, a0, a1, a2, a3, c2);                     \
      if (q2 == 0){                                                            \
        ((_Float16*)(e2op + ((CP)^1)*48))[64 + j2] = (_Float16)h;              \
        if ((T2) == TT-1) latF[j2] = fmaxf(h, 0.0f);                           \
      }                                                                        \
    } }while(0)

    // peel t=0 (cur=0)
    XSTAGE(0, 1); E1STEP(0, 0);
    __syncthreads();
    // pairs t=1(odd,cur1), t+1(even,cur0) for t=1..509
    for (int t = 1; t <= TT-3; t += 2){
      XSTAGE(t, 0);   E1STEP(t, 1);   E2STEP(t-1, 0);
      __syncthreads();
      XSTAGE(t+1, 1); E1STEP(t+1, 0); E2STEP(t, 1);
      __syncthreads();
    }
    // t=511 (cur=1)
    XSTAGE(TT-1, 0); E1STEP(TT-1, 1); E2STEP(TT-2, 0);
    __syncthreads();
    // t=512: e2 tail only (t2=511, parity 1)
    E2STEP(TT-1, 1);
    __syncthreads();
#undef XSTAGE
#undef E1STEP
#undef E2STEP
  }
  __syncthreads();
  asm volatile("" ::: "memory");   // e-loop weights die here

  //================= D-LOOP: d2 (first) || d1(lag-1 lead, LDS weights) =================
  {
    // Fill wD1L: 8192 dw, 16 per thread. idx -> (r, l, d); lane l=(qd=l&3, jd=l>>2),
    // gate g=r>>1, lane-dword m=(r&1)*4+d, f16 k0 = qd*16 + 2m within K=64.
#pragma unroll
    for (int i=0;i<16;++i){
      const int idx = i*512 + tid;
      const int r = idx >> 10, rem = idx & 1023, l = rem >> 2, d = rem & 3;
      const int jd_ = l >> 2, qd_ = l & 3, g = r >> 1, m = ((r & 1) << 2) + d;
      const int row = g*64 + jd_, k0 = qd_*16 + 2*m;
      wD1L[idx] = packh2(WhhD1[row*64+k0], WhhD1[row*64+k0+1]);
    }
    // Fill bD2L[128]: per-unit d2 bias (4 gates)
    if (tid < 128){
      float4 bb;
      bb.x = bihD2[0*128+tid] + bhhD2[0*128+tid];
      bb.y = bihD2[1*128+tid] + bhhD2[1*128+tid];
      bb.z = bihD2[2*128+tid] + bhhD2[2*128+tid];
      bb.w = bihD2[3*128+tid] + bhhD2[3*128+tid];
      bD2L[tid] = bb;
    }
    // Fill pD1L[64]: per-unit d1 latent-projection + bias (latF ready)
    if (tid < 64){
      float4 pp;
#pragma unroll
      for (int g=0; g<4; ++g){
        const int row = g*64 + tid;
        float a = bihD1[row] + bhhD1[row];
#pragma unroll
        for (int i=0;i<16;++i) a = fmaf(WihD1[row*16+i], latF[i], a);
        (&pp.x)[g] = a;
      }
      pD1L[tid] = pp;
    }

    const int qd = tid & 3, jd = tid >> 2;        // d2: unit jd in [0,128)
    half2v wD2[4][24];
#pragma unroll
    for (int g=0; g<4; ++g){
      const int row = g*128 + jd;
#pragma unroll
      for (int m=0;m<24;++m){
        const int k0 = 48*qd + 2*m;               // concat {x:64, h:128}
        const float lo = (k0   < 64)? WihD2[row*64+k0]   : WhhD2[row*128+(k0-64)];
        const float hi = (k0+1 < 64)? WihD2[row*64+k0+1] : WhhD2[row*128+(k0+1-64)];
        wD2[g][m] = mkh2(lo,hi);
      }
    }
    const bool d1act = (tid < 256);               // d1: unit = jd in [0,64), slice qd
    if (tid < 64)                dop[32 + tid] = 0u;   // hd2(-1)=0 (parity 0)
    if (tid >= 64 && tid < 96)   vhD1[tid-64] = 0u;    // hd1(-1)=0 (parity 0)
    float cd1 = 0.0f, cd2 = 0.0f;
    float* orow = out + (size_t)b * (TT*128);
    __syncthreads();

#define D2STEP(T2, C2P) do{                                                    \
      float a0=0.f, a1=0.f, a2=0.f, a3=0.f;                                    \
      const uint4* vp = (const uint4*)(dop + (C2P)*96 + qd*24);                \
      _Pragma("unroll")                                                        \
      for (int r=0;r<6;++r){                                                   \
        const uint4 u = vp[r];                                                 \
        const half2v o0=ash2(u.x),o1=ash2(u.y),o2=ash2(u.z),o3=ash2(u.w);      \
        a0=dot2(wD2[0][4*r+0],o0,a0); a1=dot2(wD2[1][4*r+0],o0,a1);            \
        a2=dot2(wD2[2][4*r+0],o0,a2); a3=dot2(wD2[3][4*r+0],o0,a3);            \
        a0=dot2(wD2[0][4*r+1],o1,a0); a1=dot2(wD2[1][4*r+1],o1,a1);            \
        a2=dot2(wD2[2][4*r+1],o1,a2); a3=dot2(wD2[3][4*r+1],o1,a3);            \
        a0=dot2(wD2[0][4*r+2],o2,a0); a1=dot2(wD2[1][4*r+2],o2,a1);            \
        a2=dot2(wD2[2][4*r+2],o2,a2); a3=dot2(wD2[3][4*r+2],o2,a3);            \
        a0=dot2(wD2[0][4*r+3],o3,a0); a1=dot2(wD2[1][4*r+3],o3,a1);            \
        a2=dot2(wD2[2][4*r+3],o3,a2); a3=dot2(wD2[3][4*r+3],o3,a3);            \
      }                                                                        \
      a0=qsum2(qsum1(a0)); a1=qsum2(qsum1(a1));                                \
      a2=qsum2(qsum1(a2)); a3=qsum2(qsum1(a3));                                \
      const float4 bb = bD2L[jd];                                              \
      a0 += bb.x; a1 += bb.y; a2 += bb.z; a3 += bb.w;                          \
      const float h = lstm_update(qd, a0, a1, a2, a3, cd2);                    \
      if (qd==0){                                                              \
        ((_Float16*)(dop + ((C2P)^1)*96))[64 + jd] = (_Float16)h;              \
        orow[(size_t)(T2)*128 + jd] = h;                                       \
      }                                                                        \
    }while(0)

#define D1STEP(T, CUR) do{ if (d1act){                                         \
      const uint4* ov = (const uint4*)(vhD1 + (CUR)*32 + qd*8);                \
      const uint4 o01 = ov[0], o23 = ov[1];                                    \
      float a0=0.f, a1=0.f, a2=0.f, a3=0.f;                                    \
      {                                                                        \
        const uint4 wA = *(const uint4*)(wD1L + 0*1024 + tid*4);               \
        const uint4 wB = *(const uint4*)(wD1L + 1*1024 + tid*4);               \
        a0=dot2(ash2(wA.x),ash2(o01.x),a0); a0=dot2(ash2(wA.y),ash2(o01.y),a0);\
        a0=dot2(ash2(wA.z),ash2(o01.z),a0); a0=dot2(ash2(wA.w),ash2(o01.w),a0);\
        a0=dot2(ash2(wB.x),ash2(o23.x),a0); a0=dot2(ash2(wB.y),ash2(o23.y),a0);\
        a0=dot2(ash2(wB.z),ash2(o23.z),a0); a0=dot2(ash2(wB.w),ash2(o23.w),a0);\
      }                                                                        \
      {                                                                        \
        const uint4 wA = *(const uint4*)(wD1L + 2*1024 + tid*4);               \
        const uint4 wB = *(const uint4*)(wD1L + 3*1024 + tid*4);               \
        a1=dot2(ash2(wA.x),ash2(o01.x),a1); a1=dot2(ash2(wA.y),ash2(o01.y),a1);\
        a1=dot2(ash2(wA.z),ash2(o01.z),a1); a1=dot2(ash2(wA.w),ash2(o01.w),a1);\
        a1=dot2(ash2(wB.x),ash2(o23.x),a1); a1=dot2(ash2(wB.y),ash2(o23.y),a1);\
        a1=dot2(ash2(wB.z),ash2(o23.z),a1); a1=dot2(ash2(wB.w),ash2(o23.w),a1);\
      }                                                                        \
      {                                                                        \
        const uint4 wA = *(const uint4*)(wD1L + 4*1024 + tid*4);               \
        const uint4 wB = *(const uint4*)(wD1L + 5*1024 + tid*4);               \
        a2=dot2(ash2(wA.x),ash2(o01.x),a2); a2=dot2(ash2(wA.y),ash2(o01.y),a2);\
        a2=dot2(ash2(wA.z),ash2(o01.z),a2); a2=dot2(ash2(wA.w),ash2(o01.w),a2);\
        a2=dot2(ash2(wB.x),ash2(o23.x),a2); a2=dot2(ash2(wB.y),ash2(o23.y),a2);\
        a2=dot2(ash2(wB.z),ash2(o23.z),a2); a2=dot2(ash2(wB.w),ash2(o23.w),a2);\
      }                                                                        \
      {                                                                        \
        const uint4 wA = *(const uint4*)(wD1L + 6*1024 + tid*4);               \
        const uint4 wB = *(const uint4*)(wD1L + 7*1024 + tid*4);               \
        a3=dot2(ash2(wA.x),ash2(o01.x),a3); a3=dot2(ash2(wA.y),ash2(o01.y),a3);\
        a3=dot2(ash2(wA.z),ash2(o01.z),a3); a3=dot2(ash2(wA.w),ash2(o01.w),a3);\
        a3=dot2(ash2(wB.x),ash2(o23.x),a3); a3=dot2(ash2(wB.y),ash2(o23.y),a3);\
        a3=dot2(ash2(wB.z),ash2(o23.z),a3); a3=dot2(ash2(wB.w),ash2(o23.w),a3);\
      }                                                                        \
      a0=qsum2(qsum1(a0)); a1=qsum2(qsum1(a1));                                \
      a2=qsum2(qsum1(a2)); a3=qsum2(qsum1(a3));                                \
      const float4 pj = pD1L[jd];                                              \
      a0 += pj.x; a1 += pj.y; a2 += pj.z; a3 += pj.w;                          \
      const float h = lstm_update(qd, a0, a1, a2, a3, cd1);                    \
      if (qd==0){                                                              \
        ((_Float16*)(vhD1 + ((CUR)^1)*32))[jd] = (_Float16)h;                  \
        ((_Float16*)(dop + (CUR)*96))[jd]      = (_Float16)fmaxf(h,0.0f);      \
      }                                                                        \
    } }while(0)

    // peel t=0 (cur=0): d1 only
    D1STEP(0, 0);
    __syncthreads();
    // pairs t=odd(cur1), t+1=even(cur0) for t=1..509
    for (int t = 1; t <= TT-3; t += 2){
      D2STEP(t-1, 0); D1STEP(t, 1);
      __syncthreads();
      D2STEP(t, 1);   D1STEP(t+1, 0);
      __syncthreads();
    }
    // t=511 (cur=1)
    D2STEP(TT-2, 0); D1STEP(TT-1, 1);
    __syncthreads();
    // t=512: d2 tail only (t2=511, parity 1)
    D2STEP(TT-1, 1);
#undef D2STEP
#undef D1STEP
  }
}

extern "C" void kernel_launch(void* const* d_in, const int* in_sizes, int n_in,
                              void* d_out, int out_size, void* d_ws, size_t ws_size,
                              hipStream_t stream) {
  const float* x      = (const float*)d_in[0];
  const float* WihE1  = (const float*)d_in[1];
  const float* WhhE1  = (const float*)d_in[2];
  const float* bihE1  = (const float*)d_in[3];
  const float* bhhE1  = (const float*)d_in[4];
  const float* WihE2  = (const float*)d_in[5];
  const float* WhhE2  = (const float*)d_in[6];
  const float* bihE2  = (const float*)d_in[7];
  const float* bhhE2  = (const float*)d_in[8];
  const float* WihD1  = (const float*)d_in[9];
  const float* WhhD1  = (const float*)d_in[10];
  const float* bihD1  = (const float*)d_in[11];
  const float* bhhD1  = (const float*)d_in[12];
  const float* WihD2  = (const float*)d_in[13];
  const float* WhhD2  = (const float*)d_in[14];
  const float* bihD2  = (const float*)d_in[15];
  const float* bhhD2  = (const float*)d_in[16];
  float* out = (float*)d_out;

  k_fused<<<BB, 512, 0, stream>>>(x,
      WihE1, WhhE1, bihE1, bhhE1,
      WihE2, WhhE2, bihE2, bhhE2,
      WihD1, WhhD1, bihD1, bhhD1,
      WihD2, WhhD2, bihD2, bhhD2,
      out);
}

// Round 15
// 758.896 us; speedup vs baseline: 1.2977x; 1.0217x over previous
//
#include <hip/hip_runtime.h>

// LSTM autoencoder, fused, TWO-LOOP pipelined kernel. 256 blocks (1/CU), 512 thr.
// r14 best: 775us, no spill (VGPR 124), 0 conflicts, VALUBusy 62% -> issue-bound.
// r15: e-loop remap to cut per-SIMD issue on the critical wave pair:
//   e1: Q=4/G=4 on waves 0-3 (r5-proven mapping; 96 dot2/lane, 96dw reg weights,
//       qsum2.qsum1 reduce [16 ops vs hsum8's 24], update on 4 waves not 8)
//   e2: wave 4, weights in 12KB LDS table (avoids 96+48=144 reg live -> spill;
//       12 conflict-free ds_read_b128/step on wave 4 only)
//   x-stage: wave 5 (depth-2 prefetch); waves 6-7 idle (barrier-only).
// d-loop unchanged from r14 (d2's 96 dot2/lane = MAC floor at this mapping).
// 2-parity rings; DPP-only reduces; quad-split activation; rcp activations;
// 1 barrier/step; unrolled x2 with compile-time parities.

#define BB 256
#define TT 512

typedef _Float16 half2v __attribute__((ext_vector_type(2)));

static __device__ __forceinline__ float dot2(half2v a, half2v b, float c){
  return __builtin_amdgcn_fdot2(a,b,c,false);
}
template<int CTRL>
static __device__ __forceinline__ float qb(float v){
  return __int_as_float(__builtin_amdgcn_update_dpp(0, __float_as_int(v), CTRL, 0xF, 0xF, true));
}
static __device__ __forceinline__ float qsum1(float v){ return v + qb<0xB1>(v); }
static __device__ __forceinline__ float qsum2(float v){ return v + qb<0x4E>(v); }
static __device__ __forceinline__ float rcp_(float v){ return __builtin_amdgcn_rcpf(v); }
static __device__ __forceinline__ unsigned packh2(float lo, float hi){
  half2v p; p.x=(_Float16)lo; p.y=(_Float16)hi;
  return __builtin_bit_cast(unsigned, p);
}
static __device__ __forceinline__ half2v ash2(unsigned u){ return __builtin_bit_cast(half2v,u); }
static __device__ __forceinline__ half2v mkh2(float lo, float hi){
  half2v p; p.x=(_Float16)lo; p.y=(_Float16)hi; return p;
}

// Quad lanes hold identical a0..a3=(i,f,g,o). Lane q activates gate q (tanh
// via 2*sigm(2v)-1), DPP quad-broadcast, update c, return h. rcp_ activations.
static __device__ __forceinline__ float lstm_update(int q, float a0, float a1,
                                                    float a2, float a3, float& c){
  float mine = a0;
  mine = (q==1) ? a1 : mine;
  mine = (q==2) ? a2 : mine;
  mine = (q==3) ? a3 : mine;
  const bool isg = (q==2);
  const float arg = isg ? (mine+mine) : mine;
  const float s   = rcp_(1.0f + __expf(-arg));
  const float act = isg ? (s+s-1.0f) : s;
  const float bi = qb<0x00>(act);
  const float bf = qb<0x55>(act);
  const float bg = qb<0xAA>(act);
  const float bo = qb<0xFF>(act);
  c = bf*c + bi*bg;
  const float s2 = rcp_(1.0f + __expf(-(c+c)));
  return bo*(s2+s2-1.0f);
}

__global__ void __launch_bounds__(512, 2) k_fused(
    const float* __restrict__ x,
    const float* __restrict__ WihE1, const float* __restrict__ WhhE1,
    const float* __restrict__ bihE1, const float* __restrict__ bhhE1,
    const float* __restrict__ WihE2, const float* __restrict__ WhhE2,
    const float* __restrict__ bihE2, const float* __restrict__ bhhE2,
    const float* __restrict__ WihD1, const float* __restrict__ WhhD1,
    const float* __restrict__ bihD1, const float* __restrict__ bhhD1,
    const float* __restrict__ WihD2, const float* __restrict__ WhhD2,
    const float* __restrict__ bihD2, const float* __restrict__ bhhD2,
    float* __restrict__ out)
{
  const int b = blockIdx.x, tid = threadIdx.x;

  __shared__ unsigned wD1L[8*1024]; // 32KB d1 weights: [r 0..7][lane 0..255][4dw]
  __shared__ unsigned e2wL[12*256]; // 12KB e2 weights: [r 0..11][lane 0..63][4dw]
  __shared__ unsigned vhE [2*96];   // e1 operand ring: x 64dw || h1 32dw (f16)
  __shared__ unsigned e2op[2*48];   // e2 ring: relu(h1) 32dw || h2 8dw || pad0 8dw
  __shared__ unsigned dop [2*96];   // d2 ring: relu(hd1) 32dw || hd2 64dw
  __shared__ unsigned vhD1[2*32];   // d1 h ring
  __shared__ float4   bD2L[128];    // d2 bias per unit (4 gates)
  __shared__ float4   pD1L[64];     // d1 latent-proj+bias per unit (4 gates)
  __shared__ float    latF[16];

  //================= E-LOOP: e1(waves 0-3) || e2(wave 4) || x(wave 5) =================
  {
    // e2 weight table fill: 3072 dw, 6 per thread.
    // idx=(g*3+rr)*256 + l*4 + d ; lane l=(q2=l&3, j2=l>>2); m=rr*4+d;
    // k0 = q2*24 + 2m within padded K=96 {Wih:64, Whh:16, pad:16}, row g*16+j2.
#pragma unroll
    for (int i=0;i<6;++i){
      const int idx = i*512 + tid;
      const int r_ = idx >> 8, rem = idx & 255, l = rem >> 2, d = rem & 3;
      const int g = r_/3, rr = r_ - 3*g, m = rr*4 + d;
      const int q2l = l & 3, j2l = l >> 2;
      const int row = g*16 + j2l, k0 = q2l*24 + 2*m;
      float lo = 0.0f, hi = 0.0f;
      if (k0 < 64)        lo = WihE2[row*64+k0];
      else if (k0 < 80)   lo = WhhE2[row*16 + (k0-64)];
      if (k0+1 < 64)      hi = WihE2[row*64+k0+1];
      else if (k0+1 < 80) hi = WhhE2[row*16 + (k0+1-64)];
      e2wL[idx] = packh2(lo, hi);
    }

    // e1: waves 0-3 (lanes 0-255). unit j=tid>>2 in [0,64), slice q=tid&3.
    const bool e1act = (tid < 256);
    const int q = tid & 3, j = tid >> 2;
    half2v w1[4][24];
    float bias1[4] = {0.f,0.f,0.f,0.f};
    if (e1act){
#pragma unroll
      for (int g=0; g<4; ++g){
        const int row = g*64 + j;
        bias1[g] = (q==0) ? (bihE1[row]+bhhE1[row]) : 0.0f;
#pragma unroll
        for (int m=0;m<24;++m){
          const int k0 = q*48 + 2*m;              // concat {x:128, h:64}
          const float lo = (k0   < 128)? WihE1[row*128+k0]   : WhhE1[row*64 + (k0-128)];
          const float hi = (k0+1 < 128)? WihE1[row*128+k0+1] : WhhE1[row*64 + (k0+1-128)];
          w1[g][m] = mkh2(lo,hi);
        }
      }
    }
    // e2: wave 4 (tid 256..319). unit j2 in [0,16), slice q2. Weights from e2wL.
    const bool e2act = (tid >= 256 && tid < 320);
    const int q2 = tid & 3, j2 = (tid & 63) >> 2;
    const int l4 = (tid & 63) * 4;                // e2wL lane offset
    float bias2[4] = {0.f,0.f,0.f,0.f};
    if (e2act && q2 == 0){
#pragma unroll
      for (int g=0; g<4; ++g) bias2[g] = bihE2[g*16+j2] + bhhE2[g*16+j2];
    }
    // x staging: wave 5 (tid 320..383), depth-2 register prefetch
    const bool xact = (tid >= 320 && tid < 384);
    const int  xl   = tid - 320;
    const float* xrow = x + (size_t)b * (TT*128);
    float2 xa, xb;
    if (xact){
      float2 v0 = *(const float2*)(xrow + 2*xl);
      vhE[xl] = packh2(v0.x, v0.y);               // x(0) -> parity 0
      xa = *(const float2*)(xrow + 128 + 2*xl);
      xb = *(const float2*)(xrow + 256 + 2*xl);
    }
    if (tid >= 128 && tid < 160) vhE[64 + (tid-128)] = 0u;  // h1(-1)=0 (parity 0)
    if (tid >= 160 && tid < 256) e2op[tid-160] = 0u;        // h2(-1)+pads=0 (both par.)
    float c1 = 0.0f, c2 = 0.0f;
    __syncthreads();

#define XSTAGE(T, NXT) do{ if (xact){                                          \
      vhE[(NXT)*96 + xl] = packh2(xa.x, xa.y);                                 \
      xa = xb;                                                                 \
      const int t3_ = ((T)+3 < TT) ? ((T)+3) : (TT-1);                         \
      xb = *(const float2*)(xrow + (size_t)t3_*128 + 2*xl);                    \
    } }while(0)

#define E1STEP(T, CUR) do{ if (e1act){                                         \
      float a0=bias1[0], a1=bias1[1], a2=bias1[2], a3=bias1[3];                \
      const uint4* vp = (const uint4*)(vhE + (CUR)*96 + q*24);                 \
      _Pragma("unroll")                                                        \
      for (int r=0;r<6;++r){                                                   \
        const uint4 u = vp[r];                                                 \
        const half2v o0=ash2(u.x), o1=ash2(u.y), o2=ash2(u.z), o3=ash2(u.w);   \
        a0=dot2(w1[0][4*r+0],o0,a0); a1=dot2(w1[1][4*r+0],o0,a1);              \
        a2=dot2(w1[2][4*r+0],o0,a2); a3=dot2(w1[3][4*r+0],o0,a3);              \
        a0=dot2(w1[0][4*r+1],o1,a0); a1=dot2(w1[1][4*r+1],o1,a1);              \
        a2=dot2(w1[2][4*r+1],o1,a2); a3=dot2(w1[3][4*r+1],o1,a3);              \
        a0=dot2(w1[0][4*r+2],o2,a0); a1=dot2(w1[1][4*r+2],o2,a1);              \
        a2=dot2(w1[2][4*r+2],o2,a2); a3=dot2(w1[3][4*r+2],o2,a3);              \
        a0=dot2(w1[0][4*r+3],o3,a0); a1=dot2(w1[1][4*r+3],o3,a1);              \
        a2=dot2(w1[2][4*r+3],o3,a2); a3=dot2(w1[3][4*r+3],o3,a3);              \
      }                                                                        \
      a0=qsum2(qsum1(a0)); a1=qsum2(qsum1(a1));                                \
      a2=qsum2(qsum1(a2)); a3=qsum2(qsum1(a3));                                \
      const float h = lstm_update(q, a0, a1, a2, a3, c1);                      \
      if (q == 0){                                                             \
        ((_Float16*)(vhE + ((CUR)^1)*96))[128 + j] = (_Float16)h;              \
        ((_Float16*)(e2op + (CUR)*48))[j]          = (_Float16)fmaxf(h, 0.0f); \
      }                                                                        \
    } }while(0)

#define E2GATE(G, AG, U0, U1, U2) do{                                          \
      const uint4 wA = *(const uint4*)(e2wL + ((G)*3+0)*256 + l4);             \
      const uint4 wB = *(const uint4*)(e2wL + ((G)*3+1)*256 + l4);             \
      const uint4 wC = *(const uint4*)(e2wL + ((G)*3+2)*256 + l4);             \
      AG=dot2(ash2(wA.x),ash2(U0.x),AG); AG=dot2(ash2(wA.y),ash2(U0.y),AG);    \
      AG=dot2(ash2(wA.z),ash2(U0.z),AG); AG=dot2(ash2(wA.w),ash2(U0.w),AG);    \
      AG=dot2(ash2(wB.x),ash2(U1.x),AG); AG=dot2(ash2(wB.y),ash2(U1.y),AG);    \
      AG=dot2(ash2(wB.z),ash2(U1.z),AG); AG=dot2(ash2(wB.w),ash2(U1.w),AG);    \
      AG=dot2(ash2(wC.x),ash2(U2.x),AG); AG=dot2(ash2(wC.y),ash2(U2.y),AG);    \
      AG=dot2(ash2(wC.z),ash2(U2.z),AG); AG=dot2(ash2(wC.w),ash2(U2.w),AG);    \
    }while(0)

#define E2STEP(T2, CP) do{ if (e2act){                                         \
      const uint4* ovp = (const uint4*)(e2op + (CP)*48 + q2*12);               \
      const uint4 u0 = ovp[0], u1 = ovp[1], u2 = ovp[2];                       \
      float a0=bias2[0], a1=bias2[1], a2=bias2[2], a3=bias2[3];                \
      E2GATE(0, a0, u0, u1, u2);                                               \
      E2GATE(1, a1, u0, u1, u2);                                               \
      E2GATE(2, a2, u0, u1, u2);                                               \
      E2GATE(3, a3, u0, u1, u2);                                               \
      a0=qsum2(qsum1(a0)); a1=qsum2(qsum1(a1));                                \
      a2=qsum2(qsum1(a2)); a3=qsum2(qsum1(a3));                                \
      const float h = lstm_update(q2, a0, a1, a2, a3, c2);                     \
      if (q2 == 0){                                                            \
        ((_Float16*)(e2op + ((CP)^1)*48))[64 + j2] = (_Float16)h;              \
        if ((T2) == TT-1) latF[j2] = fmaxf(h, 0.0f);                           \
      }                                                                        \
    } }while(0)

    // peel t=0 (cur=0)
    XSTAGE(0, 1); E1STEP(0, 0);
    __syncthreads();
    // pairs t=1(odd,cur1), t+1(even,cur0) for t=1..509
    for (int t = 1; t <= TT-3; t += 2){
      XSTAGE(t, 0);   E1STEP(t, 1);   E2STEP(t-1, 0);
      __syncthreads();
      XSTAGE(t+1, 1); E1STEP(t+1, 0); E2STEP(t, 1);
      __syncthreads();
    }
    // t=511 (cur=1)
    XSTAGE(TT-1, 0); E1STEP(TT-1, 1); E2STEP(TT-2, 0);
    __syncthreads();
    // t=512: e2 tail only (t2=511, parity 1)
    E2STEP(TT-1, 1);
    __syncthreads();
#undef XSTAGE
#undef E1STEP
#undef E2GATE
#undef E2STEP
  }
  __syncthreads();
  asm volatile("" ::: "memory");   // e-loop weights die here

  //================= D-LOOP: d2 (first) || d1(lag-1 lead, LDS weights) =================
  {
    // Fill wD1L: 8192 dw, 16 per thread. idx -> (r, l, d); lane l=(qd=l&3, jd=l>>2),
    // gate g=r>>1, lane-dword m=(r&1)*4+d, f16 k0 = qd*16 + 2m within K=64.
#pragma unroll
    for (int i=0;i<16;++i){
      const int idx = i*512 + tid;
      const int r = idx >> 10, rem = idx & 1023, l = rem >> 2, d = rem & 3;
      const int jd_ = l >> 2, qd_ = l & 3, g = r >> 1, m = ((r & 1) << 2) + d;
      const int row = g*64 + jd_, k0 = qd_*16 + 2*m;
      wD1L[idx] = packh2(WhhD1[row*64+k0], WhhD1[row*64+k0+1]);
    }
    // Fill bD2L[128]: per-unit d2 bias (4 gates)
    if (tid < 128){
      float4 bb;
      bb.x = bihD2[0*128+tid] + bhhD2[0*128+tid];
      bb.y = bihD2[1*128+tid] + bhhD2[1*128+tid];
      bb.z = bihD2[2*128+tid] + bhhD2[2*128+tid];
      bb.w = bihD2[3*128+tid] + bhhD2[3*128+tid];
      bD2L[tid] = bb;
    }
    // Fill pD1L[64]: per-unit d1 latent-projection + bias (latF ready)
    if (tid < 64){
      float4 pp;
#pragma unroll
      for (int g=0; g<4; ++g){
        const int row = g*64 + tid;
        float a = bihD1[row] + bhhD1[row];
#pragma unroll
        for (int i=0;i<16;++i) a = fmaf(WihD1[row*16+i], latF[i], a);
        (&pp.x)[g] = a;
      }
      pD1L[tid] = pp;
    }

    const int qd = tid & 3, jd = tid >> 2;        // d2: unit jd in [0,128)
    half2v wD2[4][24];
#pragma unroll
    for (int g=0; g<4; ++g){
      const int row = g*128 + jd;
#pragma unroll
      for (int m=0;m<24;++m){
        const int k0 = 48*qd + 2*m;               // concat {x:64, h:128}
        const float lo = (k0   < 64)? WihD2[row*64+k0]   : WhhD2[row*128+(k0-64)];
        const float hi = (k0+1 < 64)? WihD2[row*64+k0+1] : WhhD2[row*128+(k0+1-64)];
        wD2[g][m] = mkh2(lo,hi);
      }
    }
    const bool d1act = (tid < 256);               // d1: unit = jd in [0,64), slice qd
    if (tid < 64)                dop[32 + tid] = 0u;   // hd2(-1)=0 (parity 0)
    if (tid >= 64 && tid < 96)   vhD1[tid-64] = 0u;    // hd1(-1)=0 (parity 0)
    float cd1 = 0.0f, cd2 = 0.0f;
    float* orow = out + (size_t)b * (TT*128);
    __syncthreads();

#define D2STEP(T2, C2P) do{                                                    \
      float a0=0.f, a1=0.f, a2=0.f, a3=0.f;                                    \
      const uint4* vp = (const uint4*)(dop + (C2P)*96 + qd*24);                \
      _Pragma("unroll")                                                        \
      for (int r=0;r<6;++r){                                                   \
        const uint4 u = vp[r];                                                 \
        const half2v o0=ash2(u.x),o1=ash2(u.y),o2=ash2(u.z),o3=ash2(u.w);      \
        a0=dot2(wD2[0][4*r+0],o0,a0); a1=dot2(wD2[1][4*r+0],o0,a1);            \
        a2=dot2(wD2[2][4*r+0],o0,a2); a3=dot2(wD2[3][4*r+0],o0,a3);            \
        a0=dot2(wD2[0][4*r+1],o1,a0); a1=dot2(wD2[1][4*r+1],o1,a1);            \
        a2=dot2(wD2[2][4*r+1],o1,a2); a3=dot2(wD2[3][4*r+1],o1,a3);            \
        a0=dot2(wD2[0][4*r+2],o2,a0); a1=dot2(wD2[1][4*r+2],o2,a1);            \
        a2=dot2(wD2[2][4*r+2],o2,a2); a3=dot2(wD2[3][4*r+2],o2,a3);            \
        a0=dot2(wD2[0][4*r+3],o3,a0); a1=dot2(wD2[1][4*r+3],o3,a1);            \
        a2=dot2(wD2[2][4*r+3],o3,a2); a3=dot2(wD2[3][4*r+3],o3,a3);            \
      }                                                                        \
      a0=qsum2(qsum1(a0)); a1=qsum2(qsum1(a1));                                \
      a2=qsum2(qsum1(a2)); a3=qsum2(qsum1(a3));                                \
      const float4 bb = bD2L[jd];                                              \
      a0 += bb.x; a1 += bb.y; a2 += bb.z; a3 += bb.w;                          \
      const float h = lstm_update(qd, a0, a1, a2, a3, cd2);                    \
      if (qd==0){                                                              \
        ((_Float16*)(dop + ((C2P)^1)*96))[64 + jd] = (_Float16)h;              \
        orow[(size_t)(T2)*128 + jd] = h;                                       \
      }                                                                        \
    }while(0)

#define D1STEP(T, CUR) do{ if (d1act){                                         \
      const uint4* ov = (const uint4*)(vhD1 + (CUR)*32 + qd*8);                \
      const uint4 o01 = ov[0], o23 = ov[1];                                    \
      float a0=0.f, a1=0.f, a2=0.f, a3=0.f;                                    \
      {                                                                        \
        const uint4 wA = *(const uint4*)(wD1L + 0*1024 + tid*4);               \
        const uint4 wB = *(const uint4*)(wD1L + 1*1024 + tid*4);               \
        a0=dot2(ash2(wA.x),ash2(o01.x),a0); a0=dot2(ash2(wA.y),ash2(o01.y),a0);\
        a0=dot2(ash2(wA.z),ash2(o01.z),a0); a0=dot2(ash2(wA.w),ash2(o01.w),a0);\
        a0=dot2(ash2(wB.x),ash2(o23.x),a0); a0=dot2(ash2(wB.y),ash2(o23.y),a0);\
        a0=dot2(ash2(wB.z),ash2(o23.z),a0); a0=dot2(ash2(wB.w),ash2(o23.w),a0);\
      }                                                                        \
      {                                                                        \
        const uint4 wA = *(const uint4*)(wD1L + 2*1024 + tid*4);               \
        const uint4 wB = *(const uint4*)(wD1L + 3*1024 + tid*4);               \
        a1=dot2(ash2(wA.x),ash2(o01.x),a1); a1=dot2(ash2(wA.y),ash2(o01.y),a1);\
        a1=dot2(ash2(wA.z),ash2(o01.z),a1); a1=dot2(ash2(wA.w),ash2(o01.w),a1);\
        a1=dot2(ash2(wB.x),ash2(o23.x),a1); a1=dot2(ash2(wB.y),ash2(o23.y),a1);\
        a1=dot2(ash2(wB.z),ash2(o23.z),a1); a1=dot2(ash2(wB.w),ash2(o23.w),a1);\
      }                                                                        \
      {                                                                        \
        const uint4 wA = *(const uint4*)(wD1L + 4*1024 + tid*4);               \
        const uint4 wB = *(const uint4*)(wD1L + 5*1024 + tid*4);               \
        a2=dot2(ash2(wA.x),ash2(o01.x),a2); a2=dot2(ash2(wA.y),ash2(o01.y),a2);\
        a2=dot2(ash2(wA.z),ash2(o01.z),a2); a2=dot2(ash2(wA.w),ash2(o01.w),a2);\
        a2=dot2(ash2(wB.x),ash2(o23.x),a2); a2=dot2(ash2(wB.y),ash2(o23.y),a2);\
        a2=dot2(ash2(wB.z),ash2(o23.z),a2); a2=dot2(ash2(wB.w),ash2(o23.w),a2);\
      }                                                                        \
      {                                                                        \
        const uint4 wA = *(const uint4*)(wD1L + 6*1024 + tid*4);               \
        const uint4 wB = *(const uint4*)(wD1L + 7*1024 + tid*4);               \
        a3=dot2(ash2(wA.x),ash2(o01.x),a3); a3=dot2(ash2(wA.y),ash2(o01.y),a3);\
        a3=dot2(ash2(wA.z),ash2(o01.z),a3); a3=dot2(ash2(wA.w),ash2(o01.w),a3);\
        a3=dot2(ash2(wB.x),ash2(o23.x),a3); a3=dot2(ash2(wB.y),ash2(o23.y),a3);\
        a3=dot2(ash2(wB.z),ash2(o23.z),a3); a3=dot2(ash2(wB.w),ash2(o23.w),a3);\
      }                                                                        \
      a0=qsum2(qsum1(a0)); a1=qsum2(qsum1(a1));                                \
      a2=qsum2(qsum1(a2)); a3=qsum2(qsum1(a3));                                \
      const float4 pj = pD1L[jd];                                              \
      a0 += pj.x; a1 += pj.y; a2 += pj.z; a3 += pj.w;                          \
      const float h = lstm_update(qd, a0, a1, a2, a3, cd1);                    \
      if (qd==0){                                                              \
        ((_Float16*)(vhD1 + ((CUR)^1)*32))[jd] = (_Float16)h;                  \
        ((_Float16*)(dop + (CUR)*96))[jd]      = (_Float16)fmaxf(h,0.0f);      \
      }                                                                        \
    } }while(0)

    // peel t=0 (cur=0): d1 only
    D1STEP(0, 0);
    __syncthreads();
    // pairs t=odd(cur1), t+1=even(cur0) for t=1..509
    for (int t = 1; t <= TT-3; t += 2){
      D2STEP(t-1, 0); D1STEP(t, 1);
      __syncthreads();
      D2STEP(t, 1);   D1STEP(t+1, 0);
      __syncthreads();
    }
    // t=511 (cur=1)
    D2STEP(TT-2, 0); D1STEP(TT-1, 1);
    __syncthreads();
    // t=512: d2 tail only (t2=511, parity 1)
    D2STEP(TT-1, 1);
#undef D2STEP
#undef D1STEP
  }
}

extern "C" void kernel_launch(void* const* d_in, const int* in_sizes, int n_in,
                              void* d_out, int out_size, void* d_ws, size_t ws_size,
                              hipStream_t stream) {
  const float* x      = (const float*)d_in[0];
  const float* WihE1  = (const float*)d_in[1];
  const float* WhhE1  = (const float*)d_in[2];
  const float* bihE1  = (const float*)d_in[3];
  const float* bhhE1  = (const float*)d_in[4];
  const float* WihE2  = (const float*)d_in[5];
  const float* WhhE2  = (const float*)d_in[6];
  const float* bihE2  = (const float*)d_in[7];
  const float* bhhE2  = (const float*)d_in[8];
  const float* WihD1  = (const float*)d_in[9];
  const float* WhhD1  = (const float*)d_in[10];
  const float* bihD1  = (const float*)d_in[11];
  const float* bhhD1  = (const float*)d_in[12];
  const float* WihD2  = (const float*)d_in[13];
  const float* WhhD2  = (const float*)d_in[14];
  const float* bihD2  = (const float*)d_in[15];
  const float* bhhD2  = (const float*)d_in[16];
  float* out = (float*)d_out;

  k_fused<<<BB, 512, 0, stream>>>(x,
      WihE1, WhhE1, bihE1, bhhE1,
      WihE2, WhhE2, bihE2, bhhE2,
      WihD1, WhhD1, bihD1, bhhD1,
      WihD2, WhhD2, bihD2, bhhD2,
      out);
}

// Round 16
// 755.731 us; speedup vs baseline: 1.3031x; 1.0042x over previous
//
#include <hip/hip_runtime.h>

// LSTM autoencoder, fused, TWO-LOOP pipelined kernel. 256 blocks (1/CU), 512 thr.
// r15 best: 759us; no spill (VGPR 124), 0 conflicts, HBM at algorithmic min.
// r16: e-loop SIMD rebalance (last lever). Issue ledger r15: S0 = e1(132)+e2(96)
// = 456cy critical; S2/S3 = 264. Split e2 across waves 4-5 at Q=8/G=4 (hsum8,
// r9-proven), weights in 16KB LDS table padded K=128 (2xb128/gate, 2-way bank
// alias = free); x-stage -> wave 6 (SIMD 2). New: S0/S1 ~444, S2 ~290.
// Pre-commit: >=745us => balance exhausted => ROOFLINE next round.
//   e-loop (513): e1 waves 0-3 (Q=4/G=4, 96dw regs) || e2 waves 4-5 (Q=8/G=4,
//                 LDS weights) || x-stage wave 6.
//   d-loop (513): d2 all lanes (Q=4, 96dw) || d1 lag-1 lead lanes<256 (weights in
//                 LDS 32KB); bias/proj via LDS quad-broadcast. (unchanged)
// 2-parity rings; DPP-only reduces; quad-split activation; rcp activations;
// 1 barrier/step; unrolled x2 with compile-time parities.

#define BB 256
#define TT 512

typedef _Float16 half2v __attribute__((ext_vector_type(2)));

static __device__ __forceinline__ float dot2(half2v a, half2v b, float c){
  return __builtin_amdgcn_fdot2(a,b,c,false);
}
template<int CTRL>
static __device__ __forceinline__ float qb(float v){
  return __int_as_float(__builtin_amdgcn_update_dpp(0, __float_as_int(v), CTRL, 0xF, 0xF, true));
}
static __device__ __forceinline__ float qsum1(float v){ return v + qb<0xB1>(v); }
static __device__ __forceinline__ float qsum2(float v){ return v + qb<0x4E>(v); }
static __device__ __forceinline__ float hsum8(float v){       // 8-lane-group sum
  v = qsum1(v); v = qsum2(v); return v + qb<0x141>(v);        // row_half_mirror
}
static __device__ __forceinline__ float rcp_(float v){ return __builtin_amdgcn_rcpf(v); }
static __device__ __forceinline__ unsigned packh2(float lo, float hi){
  half2v p; p.x=(_Float16)lo; p.y=(_Float16)hi;
  return __builtin_bit_cast(unsigned, p);
}
static __device__ __forceinline__ half2v ash2(unsigned u){ return __builtin_bit_cast(half2v,u); }
static __device__ __forceinline__ half2v mkh2(float lo, float hi){
  half2v p; p.x=(_Float16)lo; p.y=(_Float16)hi; return p;
}

// Quad lanes hold identical a0..a3=(i,f,g,o). Lane q activates gate q (tanh
// via 2*sigm(2v)-1), DPP quad-broadcast, update c, return h. rcp_ activations.
static __device__ __forceinline__ float lstm_update(int q, float a0, float a1,
                                                    float a2, float a3, float& c){
  float mine = a0;
  mine = (q==1) ? a1 : mine;
  mine = (q==2) ? a2 : mine;
  mine = (q==3) ? a3 : mine;
  const bool isg = (q==2);
  const float arg = isg ? (mine+mine) : mine;
  const float s   = rcp_(1.0f + __expf(-arg));
  const float act = isg ? (s+s-1.0f) : s;
  const float bi = qb<0x00>(act);
  const float bf = qb<0x55>(act);
  const float bg = qb<0xAA>(act);
  const float bo = qb<0xFF>(act);
  c = bf*c + bi*bg;
  const float s2 = rcp_(1.0f + __expf(-(c+c)));
  return bo*(s2+s2-1.0f);
}

__global__ void __launch_bounds__(512, 2) k_fused(
    const float* __restrict__ x,
    const float* __restrict__ WihE1, const float* __restrict__ WhhE1,
    const float* __restrict__ bihE1, const float* __restrict__ bhhE1,
    const float* __restrict__ WihE2, const float* __restrict__ WhhE2,
    const float* __restrict__ bihE2, const float* __restrict__ bhhE2,
    const float* __restrict__ WihD1, const float* __restrict__ WhhD1,
    const float* __restrict__ bihD1, const float* __restrict__ bhhD1,
    const float* __restrict__ WihD2, const float* __restrict__ WhhD2,
    const float* __restrict__ bihD2, const float* __restrict__ bhhD2,
    float* __restrict__ out)
{
  const int b = blockIdx.x, tid = threadIdx.x;

  __shared__ unsigned wD1L[8*1024]; // 32KB d1 weights: [r 0..7][lane 0..255][4dw]
  __shared__ unsigned e2wT[4096];   // 16KB e2 weights: [g][o2][j2][8dw], K padded 128
  __shared__ unsigned vhE [2*96];   // e1 operand ring: x 64dw || h1 32dw (f16)
  __shared__ unsigned e2op[2*64];   // e2 ring: relu(h1) 32dw || h2 8dw || pad0 24dw
  __shared__ unsigned dop [2*96];   // d2 ring: relu(hd1) 32dw || hd2 64dw
  __shared__ unsigned vhD1[2*32];   // d1 h ring
  __shared__ float4   bD2L[128];    // d2 bias per unit (4 gates)
  __shared__ float4   pD1L[64];     // d1 latent-proj+bias per unit (4 gates)
  __shared__ float    latF[16];

  //====== E-LOOP: e1(waves 0-3) || e2(waves 4-5, Q=8) || x(wave 6) ======
  {
    // e2 weight table fill: 4096 dw, 8 per thread.
    // idx -> g=idx>>10; o2f=(idx>>7)&7; j2f=(idx>>3)&15; d=idx&7.
    // k0 = o2f*16 + 2d within padded K=128 {Wih:64, Whh:16, pad:48}, row g*16+j2f.
#pragma unroll
    for (int i=0;i<8;++i){
      const int idx = i*512 + tid;
      const int g = idx >> 10, o2f = (idx >> 7) & 7, j2f = (idx >> 3) & 15, d = idx & 7;
      const int row = g*16 + j2f, k0 = o2f*16 + 2*d;
      float lo = 0.0f, hi = 0.0f;
      if (k0 < 64)        lo = WihE2[row*64+k0];
      else if (k0 < 80)   lo = WhhE2[row*16 + (k0-64)];
      if (k0+1 < 64)      hi = WihE2[row*64+k0+1];
      else if (k0+1 < 80) hi = WhhE2[row*16 + (k0+1-64)];
      e2wT[idx] = packh2(lo, hi);
    }

    // e1: waves 0-3 (lanes 0-255). unit j=tid>>2 in [0,64), slice q=tid&3.
    const bool e1act = (tid < 256);
    const int q = tid & 3, j = tid >> 2;
    half2v w1[4][24];
    float bias1[4] = {0.f,0.f,0.f,0.f};
    if (e1act){
#pragma unroll
      for (int g=0; g<4; ++g){
        const int row = g*64 + j;
        bias1[g] = (q==0) ? (bihE1[row]+bhhE1[row]) : 0.0f;
#pragma unroll
        for (int m=0;m<24;++m){
          const int k0 = q*48 + 2*m;              // concat {x:128, h:64}
          const float lo = (k0   < 128)? WihE1[row*128+k0]   : WhhE1[row*64 + (k0-128)];
          const float hi = (k0+1 < 128)? WihE1[row*128+k0+1] : WhhE1[row*64 + (k0+1-128)];
          w1[g][m] = mkh2(lo,hi);
        }
      }
    }
    // e2: waves 4-5 (tid 256..383). i2=tid-256; slice o2=i2&7, unit j2=i2>>3.
    const bool e2act = (tid >= 256 && tid < 384);
    const int i2 = tid - 256;
    const int o2 = i2 & 7, j2 = i2 >> 3;
    const int woff = o2*128 + j2*8;               // e2wT dw offset (g adds g*1024)
    float bias2[4] = {0.f,0.f,0.f,0.f};
    if (e2act && o2 == 0){
#pragma unroll
      for (int g=0; g<4; ++g) bias2[g] = bihE2[g*16+j2] + bhhE2[g*16+j2];
    }
    // x staging: wave 6 (tid 384..447), depth-2 register prefetch
    const bool xact = (tid >= 384 && tid < 448);
    const int  xl   = tid - 384;
    const float* xrow = x + (size_t)b * (TT*128);
    float2 xa, xb;
    if (xact){
      float2 v0 = *(const float2*)(xrow + 2*xl);
      vhE[xl] = packh2(v0.x, v0.y);               // x(0) -> parity 0
      xa = *(const float2*)(xrow + 128 + 2*xl);
      xb = *(const float2*)(xrow + 256 + 2*xl);
    }
    if (tid >= 128 && tid < 160) vhE[64 + (tid-128)] = 0u;  // h1(-1)=0 (parity 0)
    if (tid >= 160 && tid < 288) e2op[tid-160] = 0u;        // e2 ring zero (both par.)
    float c1 = 0.0f, c2 = 0.0f;
    __syncthreads();

#define XSTAGE(T, NXT) do{ if (xact){                                          \
      vhE[(NXT)*96 + xl] = packh2(xa.x, xa.y);                                 \
      xa = xb;                                                                 \
      const int t3_ = ((T)+3 < TT) ? ((T)+3) : (TT-1);                         \
      xb = *(const float2*)(xrow + (size_t)t3_*128 + 2*xl);                    \
    } }while(0)

#define E1STEP(T, CUR) do{ if (e1act){                                         \
      float a0=bias1[0], a1=bias1[1], a2=bias1[2], a3=bias1[3];                \
      const uint4* vp = (const uint4*)(vhE + (CUR)*96 + q*24);                 \
      _Pragma("unroll")                                                        \
      for (int r=0;r<6;++r){                                                   \
        const uint4 u = vp[r];                                                 \
        const half2v o0=ash2(u.x), o1=ash2(u.y), o2_=ash2(u.z), o3=ash2(u.w);  \
        a0=dot2(w1[0][4*r+0],o0,a0); a1=dot2(w1[1][4*r+0],o0,a1);              \
        a2=dot2(w1[2][4*r+0],o0,a2); a3=dot2(w1[3][4*r+0],o0,a3);              \
        a0=dot2(w1[0][4*r+1],o1,a0); a1=dot2(w1[1][4*r+1],o1,a1);              \
        a2=dot2(w1[2][4*r+1],o1,a2); a3=dot2(w1[3][4*r+1],o1,a3);              \
        a0=dot2(w1[0][4*r+2],o2_,a0); a1=dot2(w1[1][4*r+2],o2_,a1);            \
        a2=dot2(w1[2][4*r+2],o2_,a2); a3=dot2(w1[3][4*r+2],o2_,a3);            \
        a0=dot2(w1[0][4*r+3],o3,a0); a1=dot2(w1[1][4*r+3],o3,a1);              \
        a2=dot2(w1[2][4*r+3],o3,a2); a3=dot2(w1[3][4*r+3],o3,a3);              \
      }                                                                        \
      a0=qsum2(qsum1(a0)); a1=qsum2(qsum1(a1));                                \
      a2=qsum2(qsum1(a2)); a3=qsum2(qsum1(a3));                                \
      const float h = lstm_update(q, a0, a1, a2, a3, c1);                      \
      if (q == 0){                                                             \
        ((_Float16*)(vhE + ((CUR)^1)*96))[128 + j] = (_Float16)h;              \
        ((_Float16*)(e2op + (CUR)*64))[j]          = (_Float16)fmaxf(h, 0.0f); \
      }                                                                        \
    } }while(0)

#define E2GATE(G, AG, U0, U1) do{                                              \
      const uint4 wA = *(const uint4*)(e2wT + (G)*1024 + woff);                \
      const uint4 wB = *(const uint4*)(e2wT + (G)*1024 + woff + 4);            \
      AG=dot2(ash2(wA.x),ash2(U0.x),AG); AG=dot2(ash2(wA.y),ash2(U0.y),AG);    \
      AG=dot2(ash2(wA.z),ash2(U0.z),AG); AG=dot2(ash2(wA.w),ash2(U0.w),AG);    \
      AG=dot2(ash2(wB.x),ash2(U1.x),AG); AG=dot2(ash2(wB.y),ash2(U1.y),AG);    \
      AG=dot2(ash2(wB.z),ash2(U1.z),AG); AG=dot2(ash2(wB.w),ash2(U1.w),AG);    \
    }while(0)

#define E2STEP(T2, CP) do{ if (e2act){                                         \
      const uint4* ovp = (const uint4*)(e2op + (CP)*64 + o2*8);                \
      const uint4 u0 = ovp[0], u1 = ovp[1];                                    \
      float a0=bias2[0], a1=bias2[1], a2=bias2[2], a3=bias2[3];                \
      E2GATE(0, a0, u0, u1);                                                   \
      E2GATE(1, a1, u0, u1);                                                   \
      E2GATE(2, a2, u0, u1);                                                   \
      E2GATE(3, a3, u0, u1);                                                   \
      a0=hsum8(a0); a1=hsum8(a1); a2=hsum8(a2); a3=hsum8(a3);                  \
      const float h = lstm_update(tid & 3, a0, a1, a2, a3, c2);                \
      if (o2 == 0){                                                            \
        ((_Float16*)(e2op + ((CP)^1)*64))[64 + j2] = (_Float16)h;              \
        if ((T2) == TT-1) latF[j2] = fmaxf(h, 0.0f);                           \
      }                                                                        \
    } }while(0)

    // peel t=0 (cur=0)
    XSTAGE(0, 1); E1STEP(0, 0);
    __syncthreads();
    // pairs t=1(odd,cur1), t+1(even,cur0) for t=1..509
    for (int t = 1; t <= TT-3; t += 2){
      XSTAGE(t, 0);   E1STEP(t, 1);   E2STEP(t-1, 0);
      __syncthreads();
      XSTAGE(t+1, 1); E1STEP(t+1, 0); E2STEP(t, 1);
      __syncthreads();
    }
    // t=511 (cur=1)
    XSTAGE(TT-1, 0); E1STEP(TT-1, 1); E2STEP(TT-2, 0);
    __syncthreads();
    // t=512: e2 tail only (t2=511, parity 1)
    E2STEP(TT-1, 1);
    __syncthreads();
#undef XSTAGE
#undef E1STEP
#undef E2GATE
#undef E2STEP
  }
  __syncthreads();
  asm volatile("" ::: "memory");   // e-loop weights die here

  //================= D-LOOP: d2 (first) || d1(lag-1 lead, LDS weights) =================
  {
    // Fill wD1L: 8192 dw, 16 per thread. idx -> (r, l, d); lane l=(qd=l&3, jd=l>>2),
    // gate g=r>>1, lane-dword m=(r&1)*4+d, f16 k0 = qd*16 + 2m within K=64.
#pragma unroll
    for (int i=0;i<16;++i){
      const int idx = i*512 + tid;
      const int r = idx >> 10, rem = idx & 1023, l = rem >> 2, d = rem & 3;
      const int jd_ = l >> 2, qd_ = l & 3, g = r >> 1, m = ((r & 1) << 2) + d;
      const int row = g*64 + jd_, k0 = qd_*16 + 2*m;
      wD1L[idx] = packh2(WhhD1[row*64+k0], WhhD1[row*64+k0+1]);
    }
    // Fill bD2L[128]: per-unit d2 bias (4 gates)
    if (tid < 128){
      float4 bb;
      bb.x = bihD2[0*128+tid] + bhhD2[0*128+tid];
      bb.y = bihD2[1*128+tid] + bhhD2[1*128+tid];
      bb.z = bihD2[2*128+tid] + bhhD2[2*128+tid];
      bb.w = bihD2[3*128+tid] + bhhD2[3*128+tid];
      bD2L[tid] = bb;
    }
    // Fill pD1L[64]: per-unit d1 latent-projection + bias (latF ready)
    if (tid < 64){
      float4 pp;
#pragma unroll
      for (int g=0; g<4; ++g){
        const int row = g*64 + tid;
        float a = bihD1[row] + bhhD1[row];
#pragma unroll
        for (int i=0;i<16;++i) a = fmaf(WihD1[row*16+i], latF[i], a);
        (&pp.x)[g] = a;
      }
      pD1L[tid] = pp;
    }

    const int qd = tid & 3, jd = tid >> 2;        // d2: unit jd in [0,128)
    half2v wD2[4][24];
#pragma unroll
    for (int g=0; g<4; ++g){
      const int row = g*128 + jd;
#pragma unroll
      for (int m=0;m<24;++m){
        const int k0 = 48*qd + 2*m;               // concat {x:64, h:128}
        const float lo = (k0   < 64)? WihD2[row*64+k0]   : WhhD2[row*128+(k0-64)];
        const float hi = (k0+1 < 64)? WihD2[row*64+k0+1] : WhhD2[row*128+(k0+1-64)];
        wD2[g][m] = mkh2(lo,hi);
      }
    }
    const bool d1act = (tid < 256);               // d1: unit = jd in [0,64), slice qd
    if (tid < 64)                dop[32 + tid] = 0u;   // hd2(-1)=0 (parity 0)
    if (tid >= 64 && tid < 96)   vhD1[tid-64] = 0u;    // hd1(-1)=0 (parity 0)
    float cd1 = 0.0f, cd2 = 0.0f;
    float* orow = out + (size_t)b * (TT*128);
    __syncthreads();

#define D2STEP(T2, C2P) do{                                                    \
      float a0=0.f, a1=0.f, a2=0.f, a3=0.f;                                    \
      const uint4* vp = (const uint4*)(dop + (C2P)*96 + qd*24);                \
      _Pragma("unroll")                                                        \
      for (int r=0;r<6;++r){                                                   \
        const uint4 u = vp[r];                                                 \
        const half2v o0=ash2(u.x),o1=ash2(u.y),o2=ash2(u.z),o3=ash2(u.w);      \
        a0=dot2(wD2[0][4*r+0],o0,a0); a1=dot2(wD2[1][4*r+0],o0,a1);            \
        a2=dot2(wD2[2][4*r+0],o0,a2); a3=dot2(wD2[3][4*r+0],o0,a3);            \
        a0=dot2(wD2[0][4*r+1],o1,a0); a1=dot2(wD2[1][4*r+1],o1,a1);            \
        a2=dot2(wD2[2][4*r+1],o1,a2); a3=dot2(wD2[3][4*r+1],o1,a3);            \
        a0=dot2(wD2[0][4*r+2],o2,a0); a1=dot2(wD2[1][4*r+2],o2,a1);            \
        a2=dot2(wD2[2][4*r+2],o2,a2); a3=dot2(wD2[3][4*r+2],o2,a3);            \
        a0=dot2(wD2[0][4*r+3],o3,a0); a1=dot2(wD2[1][4*r+3],o3,a1);            \
        a2=dot2(wD2[2][4*r+3],o3,a2); a3=dot2(wD2[3][4*r+3],o3,a3);            \
      }                                                                        \
      a0=qsum2(qsum1(a0)); a1=qsum2(qsum1(a1));                                \
      a2=qsum2(qsum1(a2)); a3=qsum2(qsum1(a3));                                \
      const float4 bb = bD2L[jd];                                              \
      a0 += bb.x; a1 += bb.y; a2 += bb.z; a3 += bb.w;                          \
      const float h = lstm_update(qd, a0, a1, a2, a3, cd2);                    \
      if (qd==0){                                                              \
        ((_Float16*)(dop + ((C2P)^1)*96))[64 + jd] = (_Float16)h;              \
        orow[(size_t)(T2)*128 + jd] = h;                                       \
      }                                                                        \
    }while(0)

#define D1STEP(T, CUR) do{ if (d1act){                                         \
      const uint4* ov = (const uint4*)(vhD1 + (CUR)*32 + qd*8);                \
      const uint4 o01 = ov[0], o23 = ov[1];                                    \
      float a0=0.f, a1=0.f, a2=0.f, a3=0.f;                                    \
      {                                                                        \
        const uint4 wA = *(const uint4*)(wD1L + 0*1024 + tid*4);               \
        const uint4 wB = *(const uint4*)(wD1L + 1*1024 + tid*4);               \
        a0=dot2(ash2(wA.x),ash2(o01.x),a0); a0=dot2(ash2(wA.y),ash2(o01.y),a0);\
        a0=dot2(ash2(wA.z),ash2(o01.z),a0); a0=dot2(ash2(wA.w),ash2(o01.w),a0);\
        a0=dot2(ash2(wB.x),ash2(o23.x),a0); a0=dot2(ash2(wB.y),ash2(o23.y),a0);\
        a0=dot2(ash2(wB.z),ash2(o23.z),a0); a0=dot2(ash2(wB.w),ash2(o23.w),a0);\
      }                                                                        \
      {                                                                        \
        const uint4 wA = *(const uint4*)(wD1L + 2*1024 + tid*4);               \
        const uint4 wB = *(const uint4*)(wD1L + 3*1024 + tid*4);               \
        a1=dot2(ash2(wA.x),ash2(o01.x),a1); a1=dot2(ash2(wA.y),ash2(o01.y),a1);\
        a1=dot2(ash2(wA.z),ash2(o01.z),a1); a1=dot2(ash2(wA.w),ash2(o01.w),a1);\
        a1=dot2(ash2(wB.x),ash2(o23.x),a1); a1=dot2(ash2(wB.y),ash2(o23.y),a1);\
        a1=dot2(ash2(wB.z),ash2(o23.z),a1); a1=dot2(ash2(wB.w),ash2(o23.w),a1);\
      }                                                                        \
      {                                                                        \
        const uint4 wA = *(const uint4*)(wD1L + 4*1024 + tid*4);               \
        const uint4 wB = *(const uint4*)(wD1L + 5*1024 + tid*4);               \
        a2=dot2(ash2(wA.x),ash2(o01.x),a2); a2=dot2(ash2(wA.y),ash2(o01.y),a2);\
        a2=dot2(ash2(wA.z),ash2(o01.z),a2); a2=dot2(ash2(wA.w),ash2(o01.w),a2);\
        a2=dot2(ash2(wB.x),ash2(o23.x),a2); a2=dot2(ash2(wB.y),ash2(o23.y),a2);\
        a2=dot2(ash2(wB.z),ash2(o23.z),a2); a2=dot2(ash2(wB.w),ash2(o23.w),a2);\
      }                                                                        \
      {                                                                        \
        const uint4 wA = *(const uint4*)(wD1L + 6*1024 + tid*4);               \
        const uint4 wB = *(const uint4*)(wD1L + 7*1024 + tid*4);               \
        a3=dot2(ash2(wA.x),ash2(o01.x),a3); a3=dot2(ash2(wA.y),ash2(o01.y),a3);\
        a3=dot2(ash2(wA.z),ash2(o01.z),a3); a3=dot2(ash2(wA.w),ash2(o01.w),a3);\
        a3=dot2(ash2(wB.x),ash2(o23.x),a3); a3=dot2(ash2(wB.y),ash2(o23.y),a3);\
        a3=dot2(ash2(wB.z),ash2(o23.z),a3); a3=dot2(ash2(wB.w),ash2(o23.w),a3);\
      }                                                                        \
      a0=qsum2(qsum1(a0)); a1=qsum2(qsum1(a1));                                \
      a2=qsum2(qsum1(a2)); a3=qsum2(qsum1(a3));                                \
      const float4 pj = pD1L[jd];                                              \
      a0 += pj.x; a1 += pj.y; a2 += pj.z; a3 += pj.w;                          \
      const float h = lstm_update(qd, a0, a1, a2, a3, cd1);                    \
      if (qd==0){                                                              \
        ((_Float16*)(vhD1 + ((CUR)^1)*32))[jd] = (_Float16)h;                  \
        ((_Float16*)(dop + (CUR)*96))[jd]      = (_Float16)fmaxf(h,0.0f);      \
      }                                                                        \
    } }while(0)

    // peel t=0 (cur=0): d1 only
    D1STEP(0, 0);
    __syncthreads();
    // pairs t=odd(cur1), t+1=even(cur0) for t=1..509
    for (int t = 1; t <= TT-3; t += 2){
      D2STEP(t-1, 0); D1STEP(t, 1);
      __syncthreads();
      D2STEP(t, 1);   D1STEP(t+1, 0);
      __syncthreads();
    }
    // t=511 (cur=1)
    D2STEP(TT-2, 0); D1STEP(TT-1, 1);
    __syncthreads();
    // t=512: d2 tail only (t2=511, parity 1)
    D2STEP(TT-1, 1);
#undef D2STEP
#undef D1STEP
  }
}

extern "C" void kernel_launch(void* const* d_in, const int* in_sizes, int n_in,
                              void* d_out, int out_size, void* d_ws, size_t ws_size,
                              hipStream_t stream) {
  const float* x      = (const float*)d_in[0];
  const float* WihE1  = (const float*)d_in[1];
  const float* WhhE1  = (const float*)d_in[2];
  const float* bihE1  = (const float*)d_in[3];
  const float* bhhE1  = (const float*)d_in[4];
  const float* WihE2  = (const float*)d_in[5];
  const float* WhhE2  = (const float*)d_in[6];
  const float* bihE2  = (const float*)d_in[7];
  const float* bhhE2  = (const float*)d_in[8];
  const float* WihD1  = (const float*)d_in[9];
  const float* WhhD1  = (const float*)d_in[10];
  const float* bihD1  = (const float*)d_in[11];
  const float* bhhD1  = (const float*)d_in[12];
  const float* WihD2  = (const float*)d_in[13];
  const float* WhhD2  = (const float*)d_in[14];
  const float* bihD2  = (const float*)d_in[15];
  const float* bhhD2  = (const float*)d_in[16];
  float* out = (float*)d_out;

  k_fused<<<BB, 512, 0, stream>>>(x,
      WihE1, WhhE1, bihE1, bhhE1,
      WihE2, WhhE2, bihE2, bhhE2,
      WihD1, WhhD1, bihD1, bhhD1,
      WihD2, WhhD2, bihD2, bhhD2,
      out);
}